// Round 12
// baseline (127.219 us; speedup 1.0000x reference)
//
#include <hip/hip_runtime.h>
#include <hip/hip_bf16.h>

typedef __attribute__((ext_vector_type(8))) short short8v;
typedef __attribute__((ext_vector_type(4))) float f32x4;

#define L_SEQ 2048
#define D_DIM 1024
#define N_DIM 16
#define T_CHUNK 32
#define NCHUNK (L_SEQ / T_CHUNK)  // 64
#define EPS_DISC 1e-9f

__device__ __forceinline__ float softplusf(float x) {
    return (x > 15.f) ? x : __logf(1.f + __expf(x));
}

__device__ __forceinline__ unsigned short f2bf(float f) {
    unsigned int u = __float_as_uint(f);
    u += 0x7FFFu + ((u >> 16) & 1u);   // RNE
    return (unsigned short)(u >> 16);
}
__device__ __forceinline__ unsigned int pack2(float a, float b) {
    return (unsigned int)f2bf(a) | ((unsigned int)f2bf(b) << 16);
}
__device__ __forceinline__ float dot4(float4 a, float4 b) {
    return a.x * b.x + a.y * b.y + a.z * b.z + a.w * b.w;
}

// ============ K_MV: h0 matvec, fill-kernel-shaped ============================
// 8192 blocks x 256 threads; block owns 2 rows (1536 float4 = 24 KB).
// Per thread: 6 independent contiguous float4 loads, no LDS staging of w,
// no barriers in the hot path. Row split is compile-time (j<3 / j>=3).
__global__ __launch_bounds__(256, 4) void k_mv(const float* __restrict__ u,
                                               const float* __restrict__ init_w,
                                               const float* __restrict__ init_b,
                                               float* __restrict__ h0) {
    __shared__ float red[8];                 // 4 waves x 2 rows
    const int slab = blockIdx.x;             // 0..8191
    const int t = threadIdx.x;
    const int wv = t >> 6, lane = t & 63;

    const float4* u4 = (const float4*)u;
    const float4 u0 = u4[t];
    const float4 u1 = u4[t + 256];
    const float4 u2 = u4[t + 512];

    const float4* w4 = (const float4*)init_w + (size_t)slab * 1536;
    // row 0: j = 0,1,2 ; row 1: j = 3,4,5 (same u columns)
    const float4 w0 = w4[t];
    const float4 w1 = w4[t + 256];
    const float4 w2 = w4[t + 512];
    const float4 w3 = w4[t + 768];
    const float4 w4v = w4[t + 1024];
    const float4 w5 = w4[t + 1280];

    float acc0 = dot4(w0, u0) + dot4(w1, u1) + dot4(w2, u2);
    float acc1 = dot4(w3, u0) + dot4(w4v, u1) + dot4(w5, u2);

#pragma unroll
    for (int m = 32; m >= 1; m >>= 1) {
        acc0 += __shfl_down(acc0, m);
        acc1 += __shfl_down(acc1, m);
    }
    if (lane == 0) { red[wv] = acc0; red[wv + 4] = acc1; }
    __syncthreads();
    if (t < 2) {
        const float s = red[t * 4 + 0] + red[t * 4 + 1] + red[t * 4 + 2] + red[t * 4 + 3];
        const int row = slab * 2 + t;
        h0[row] = s + init_b[row];
    }
}

// ============ K_GEMM_BC: dt GEMM (blocks 0..255) + B/C GEMV (256..511) =======
__global__ __launch_bounds__(256) void k_gemm_bc(const float* __restrict__ u,
                                                 const float* __restrict__ dt_w,
                                                 const float* __restrict__ dt_b,
                                                 const float* __restrict__ B_w,
                                                 const float* __restrict__ B_b,
                                                 const float* __restrict__ C_w,
                                                 const float* __restrict__ C_b,
                                                 float* __restrict__ dt,
                                                 float* __restrict__ Bm,
                                                 float* __restrict__ Cm) {
    __shared__ unsigned int smem[3072];      // 12 KB gemm staging
    const int b = blockIdx.x;
    const int t = threadIdx.x;

    if (b < 256) {
        // ---- dt GEMM tile: BM=64 x BN=128 x BK=32, bf16 MFMA ----
        unsigned int* As = smem;             // 64*16
        unsigned int* Bs = smem + 1024;      // 128*16
        const int bm = b & 31;
        const int bn = b >> 5;
        const int lane = t & 63;
        const int wn   = t >> 6;
        const int lrow = lane & 15, lq = lane >> 4;

        const int arow = t >> 2, aq = t & 3;
        const int brow = t >> 1, bhalf = t & 1;

        const float* uptr = u + (bm * 64 + arow) * 1024 + aq * 8;
        const float* wptr = dt_w + (bn * 128 + brow) * 1024 + bhalf * 16;

        f32x4 acc[4][2];
#pragma unroll
        for (int mi = 0; mi < 4; ++mi)
#pragma unroll
            for (int ni = 0; ni < 2; ++ni) acc[mi][ni] = (f32x4){0.f, 0.f, 0.f, 0.f};

        for (int k0 = 0; k0 < 1024; k0 += 32) {
            __syncthreads();
            {
                const float4* p = (const float4*)(uptr + k0);
                float4 a0 = p[0], a1 = p[1];
                uint4 ca = make_uint4(pack2(a0.x, a0.y), pack2(a0.z, a0.w),
                                      pack2(a1.x, a1.y), pack2(a1.z, a1.w));
                const int akb = aq ^ ((arow >> 1) & 3);
                *(uint4*)&As[arow * 16 + akb * 4] = ca;

                const float4* q = (const float4*)(wptr + k0);
                float4 b0 = q[0], b1 = q[1], b2 = q[2], b3 = q[3];
                uint4 d0 = make_uint4(pack2(b0.x, b0.y), pack2(b0.z, b0.w),
                                      pack2(b1.x, b1.y), pack2(b1.z, b1.w));
                uint4 d1 = make_uint4(pack2(b2.x, b2.y), pack2(b2.z, b2.w),
                                      pack2(b3.x, b3.y), pack2(b3.z, b3.w));
                const int bswz = (brow >> 1) & 3;
                const int kb0 = (bhalf * 2) ^ bswz, kb1 = (bhalf * 2 + 1) ^ bswz;
                *(uint4*)&Bs[brow * 16 + kb0 * 4] = d0;
                *(uint4*)&Bs[brow * 16 + kb1 * 4] = d1;
            }
            __syncthreads();
            short8v af[4], bf[2];
#pragma unroll
            for (int mi = 0; mi < 4; ++mi) {
                const int ar = mi * 16 + lrow;
                const int kb = lq ^ ((ar >> 1) & 3);
                af[mi] = *(const short8v*)&As[ar * 16 + kb * 4];
            }
#pragma unroll
            for (int ni = 0; ni < 2; ++ni) {
                const int br = wn * 32 + ni * 16 + lrow;
                const int kb = lq ^ ((br >> 1) & 3);
                bf[ni] = *(const short8v*)&Bs[br * 16 + kb * 4];
            }
#pragma unroll
            for (int mi = 0; mi < 4; ++mi)
#pragma unroll
                for (int ni = 0; ni < 2; ++ni)
                    acc[mi][ni] = __builtin_amdgcn_mfma_f32_16x16x32_bf16(af[mi], bf[ni], acc[mi][ni], 0, 0, 0);
        }

#pragma unroll
        for (int mi = 0; mi < 4; ++mi)
#pragma unroll
            for (int ni = 0; ni < 2; ++ni) {
                const int cg = bn * 128 + wn * 32 + ni * 16 + lrow;
                const float bv = dt_b[cg];
#pragma unroll
                for (int j = 0; j < 4; ++j) {
                    const int rg = bm * 64 + mi * 16 + lq * 4 + j;
                    dt[rg * 1024 + cg] = softplusf(acc[mi][ni][j] + bv);
                }
            }
    } else {
        // ---- B/C GEMV: 8 rows/block, 2 rows/wave ----
        const int s2 = b - 256;
        const int wv = t >> 6, lane = t & 63;
#pragma unroll
        for (int rep = 0; rep < 2; ++rep) {
            const int l = s2 * 8 + wv * 2 + rep;
            const float4* u4 = (const float4*)(u + l * 1024);
            float4 ur[4];
#pragma unroll
            for (int i = 0; i < 4; ++i) ur[i] = u4[i * 64 + lane];
#pragma unroll 4
            for (int c = 0; c < 32; ++c) {
                const float4* wr = (const float4*)((c < 16) ? (B_w + c * 1024)
                                                            : (C_w + (c - 16) * 1024));
                float sv = 0.f;
#pragma unroll
                for (int i = 0; i < 4; ++i) sv += dot4(ur[i], wr[i * 64 + lane]);
#pragma unroll
                for (int off = 32; off > 0; off >>= 1) sv += __shfl_down(sv, off);
                if (lane == 0) {
                    if (c < 16) Bm[l * 16 + c] = sv + B_b[c];
                    else        Cm[l * 16 + (c - 16)] = sv + C_b[c - 16];
                }
            }
        }
    }
}

// ============ K_P1: per-chunk (prod dA, local h with h_in=0) =================
__global__ __launch_bounds__(256) void k_p1(const float* __restrict__ dt,
                                            const float* __restrict__ Bm,
                                            const float* __restrict__ u,
                                            const float* __restrict__ A_log,
                                            float* __restrict__ ap,
                                            float* __restrict__ hl) {
    const int t    = threadIdx.x;
    const int c    = blockIdx.x >> 3;
    const int dblk = blockIdx.x & 7;
    const int dd   = t >> 1;
    const int nh   = t & 1;
    const int d    = dblk * 128 + dd;
    float An[8];
#pragma unroll
    for (int n = 0; n < 8; ++n) An[n] = -__expf(A_log[nh * 8 + n]);
    float h[8], p[8];
#pragma unroll
    for (int n = 0; n < 8; ++n) { h[n] = 0.f; p[n] = 1.f; }

    const int l0 = c * T_CHUNK;
    for (int i = 0; i < T_CHUNK; ++i) {
        const int l = l0 + i;
        const float dtld = dt[l * D_DIM + d];
        const float uld  = u[l * D_DIM + d];
        const float4 b0 = *(const float4*)&Bm[l * 16 + nh * 8];
        const float4 b1 = *(const float4*)&Bm[l * 16 + nh * 8 + 4];
        auto body = [&](int n, float bn) {
            const float x = dtld * An[n];
            const float e = __expf(x);
            const float coef = (e - 1.f) * __builtin_amdgcn_rcpf(x + EPS_DISC);
            const float bu = coef * bn * uld;
            p[n] *= e;
            h[n] = fmaf(e, h[n], bu);
        };
        body(0, b0.x); body(1, b0.y); body(2, b0.z); body(3, b0.w);
        body(4, b1.x); body(5, b1.y); body(6, b1.z); body(7, b1.w);
    }
    const int base = c * (D_DIM * N_DIM) + d * 16 + nh * 8;
    *(float4*)&ap[base + 0] = make_float4(p[0], p[1], p[2], p[3]);
    *(float4*)&ap[base + 4] = make_float4(p[4], p[5], p[6], p[7]);
    *(float4*)&hl[base + 0] = make_float4(h[0], h[1], h[2], h[3]);
    *(float4*)&hl[base + 4] = make_float4(h[4], h[5], h[6], h[7]);
}

// ============ K_P2: chunk-level scan (64 steps) ==============================
__global__ __launch_bounds__(64) void k_p2(const float* __restrict__ h0,
                                           float* __restrict__ ap,
                                           const float* __restrict__ hl) {
    const int ch = blockIdx.x * 64 + threadIdx.x;
    float h = h0[ch];
#pragma unroll 8
    for (int c = 0; c < NCHUNK; ++c) {
        const int idx = c * (D_DIM * N_DIM) + ch;
        const float a = ap[idx];
        const float b = hl[idx];
        ap[idx] = h;
        h = fmaf(a, h, b);
    }
}

// ============ K_P3: recompute with carry-in, fused epilogue ==================
__global__ __launch_bounds__(256) void k_p3(const float* __restrict__ dt,
                                            const float* __restrict__ Bm,
                                            const float* __restrict__ Cm,
                                            const float* __restrict__ u,
                                            const float* __restrict__ A_log,
                                            const float* __restrict__ hstart,
                                            const float* __restrict__ D_w,
                                            const float* __restrict__ scale,
                                            float* __restrict__ out) {
    const int t    = threadIdx.x;
    const int c    = blockIdx.x >> 3;
    const int dblk = blockIdx.x & 7;
    const int dd   = t >> 1;
    const int nh   = t & 1;
    const int d    = dblk * 128 + dd;
    float An[8];
#pragma unroll
    for (int n = 0; n < 8; ++n) An[n] = -__expf(A_log[nh * 8 + n]);
    float h[8];
    const int base = c * (D_DIM * N_DIM) + d * 16 + nh * 8;
    {
        float4 h0v = *(const float4*)&hstart[base + 0];
        float4 h1v = *(const float4*)&hstart[base + 4];
        h[0] = h0v.x; h[1] = h0v.y; h[2] = h0v.z; h[3] = h0v.w;
        h[4] = h1v.x; h[5] = h1v.y; h[6] = h1v.z; h[7] = h1v.w;
    }
    const float scl = fmaxf(scale[0], 0.5f);
    const float dw = D_w[d];
    const int l0 = c * T_CHUNK;
    for (int i = 0; i < T_CHUNK; ++i) {
        const int l = l0 + i;
        const float dtld = dt[l * D_DIM + d];
        const float uld  = u[l * D_DIM + d];
        const float4 b0 = *(const float4*)&Bm[l * 16 + nh * 8];
        const float4 b1 = *(const float4*)&Bm[l * 16 + nh * 8 + 4];
        const float4 c0 = *(const float4*)&Cm[l * 16 + nh * 8];
        const float4 c1 = *(const float4*)&Cm[l * 16 + nh * 8 + 4];
        float y = 0.f;
        auto body = [&](int n, float bn, float cn) {
            const float x = dtld * An[n];
            const float e = __expf(x);
            const float coef = (e - 1.f) * __builtin_amdgcn_rcpf(x + EPS_DISC);
            const float bu = coef * bn * uld;
            h[n] = fmaf(e, h[n], bu);
            y = fmaf(cn, h[n], y);
        };
        body(0, b0.x, c0.x); body(1, b0.y, c0.y); body(2, b0.z, c0.z); body(3, b0.w, c0.w);
        body(4, b1.x, c1.x); body(5, b1.y, c1.y); body(6, b1.z, c1.z); body(7, b1.w, c1.w);
        y += __shfl_xor(y, 1);
        if (nh == 0) {
            const float yv = fmaf(dw, uld, y);
            out[l * D_DIM + d] = softplusf(yv) * scl;
        }
    }
}

extern "C" void kernel_launch(void* const* d_in, const int* in_sizes, int n_in,
                              void* d_out, int out_size, void* d_ws, size_t ws_size,
                              hipStream_t stream) {
    const float* u      = (const float*)d_in[0];
    const float* A_log  = (const float*)d_in[1];
    const float* dt_w   = (const float*)d_in[2];
    const float* dt_b   = (const float*)d_in[3];
    const float* B_w    = (const float*)d_in[4];
    const float* B_b    = (const float*)d_in[5];
    const float* C_w    = (const float*)d_in[6];
    const float* C_b    = (const float*)d_in[7];
    const float* D_w    = (const float*)d_in[8];
    const float* scale  = (const float*)d_in[9];
    const float* init_w = (const float*)d_in[10];
    const float* init_b = (const float*)d_in[11];
    float* out = (float*)d_out;

    float* ws = (float*)d_ws;
    float* dt = ws;                        // 2048*1024 = 2097152
    float* Bm = dt + 2097152;              // 32768
    float* Cm = Bm + 32768;                // 32768
    float* h0 = Cm + 32768;                // 16384
    float* ap = h0 + 16384;                // 64*16384 = 1048576
    float* hl = ap + 1048576;              // 1048576

    hipLaunchKernelGGL(k_mv,      dim3(8192), dim3(256), 0, stream, u, init_w, init_b, h0);
    hipLaunchKernelGGL(k_gemm_bc, dim3(512),  dim3(256), 0, stream,
                       u, dt_w, dt_b, B_w, B_b, C_w, C_b, dt, Bm, Cm);
    hipLaunchKernelGGL(k_p1, dim3(512), dim3(256), 0, stream, dt, Bm, u, A_log, ap, hl);
    hipLaunchKernelGGL(k_p2, dim3(256), dim3(64), 0, stream, h0, ap, hl);
    hipLaunchKernelGGL(k_p3, dim3(512), dim3(256), 0, stream, dt, Bm, Cm, u, A_log, ap, D_w, scale, out);
}

// Round 13
// 115.039 us; speedup vs baseline: 1.1059x; 1.1059x over previous
//
#include <hip/hip_runtime.h>
#include <hip/hip_bf16.h>

typedef __attribute__((ext_vector_type(8))) short short8v;
typedef __attribute__((ext_vector_type(4))) float f32x4;

#define L_SEQ 2048
#define D_DIM 1024
#define N_DIM 16
#define T_CHUNK 32
#define NCHUNK (L_SEQ / T_CHUNK)  // 64
#define EPS_DISC 1e-9f
#define MV_SPLIT 4915             // mv slabs in D1 (of 8192); rest ride with p1

__device__ __forceinline__ float softplusf(float x) {
    return (x > 15.f) ? x : __logf(1.f + __expf(x));
}

__device__ __forceinline__ unsigned short f2bf(float f) {
    unsigned int u = __float_as_uint(f);
    u += 0x7FFFu + ((u >> 16) & 1u);   // RNE
    return (unsigned short)(u >> 16);
}
__device__ __forceinline__ unsigned int pack2(float a, float b) {
    return (unsigned int)f2bf(a) | ((unsigned int)f2bf(b) << 16);
}
__device__ __forceinline__ float dot4(float4 a, float4 b) {
    return a.x * b.x + a.y * b.y + a.z * b.z + a.w * b.w;
}

// ---- mv slab body: 2 rows per slab, fill-kernel-shaped (no big LDS) --------
__device__ __forceinline__ void mv_slab(int slab, int t,
                                        const float* __restrict__ u,
                                        const float* __restrict__ init_w,
                                        const float* __restrict__ init_b,
                                        float* __restrict__ h0,
                                        float* red /*>=8 floats LDS*/) {
    const int wv = t >> 6, lane = t & 63;
    const float4* u4 = (const float4*)u;
    const float4 u0 = u4[t];
    const float4 u1 = u4[t + 256];
    const float4 u2 = u4[t + 512];

    const float4* w4 = (const float4*)init_w + (size_t)slab * 1536;
    const float4 w0 = w4[t];
    const float4 w1 = w4[t + 256];
    const float4 w2 = w4[t + 512];
    const float4 w3 = w4[t + 768];
    const float4 w4v = w4[t + 1024];
    const float4 w5 = w4[t + 1280];

    float acc0 = dot4(w0, u0) + dot4(w1, u1) + dot4(w2, u2);
    float acc1 = dot4(w3, u0) + dot4(w4v, u1) + dot4(w5, u2);

#pragma unroll
    for (int m = 32; m >= 1; m >>= 1) {
        acc0 += __shfl_down(acc0, m);
        acc1 += __shfl_down(acc1, m);
    }
    if (lane == 0) { red[wv] = acc0; red[wv + 4] = acc1; }
    __syncthreads();
    if (t < 2) {
        const float s = red[t * 4 + 0] + red[t * 4 + 1] + red[t * 4 + 2] + red[t * 4 + 3];
        const int row = slab * 2 + t;
        h0[row] = s + init_b[row];
    }
}

// ============ D1: gemm (0..255) + bc (256..511) + mv slabs [0,MV_SPLIT) ======
__global__ __launch_bounds__(256) void k_d1(const float* __restrict__ u,
                                            const float* __restrict__ dt_w,
                                            const float* __restrict__ dt_b,
                                            const float* __restrict__ B_w,
                                            const float* __restrict__ B_b,
                                            const float* __restrict__ C_w,
                                            const float* __restrict__ C_b,
                                            const float* __restrict__ init_w,
                                            const float* __restrict__ init_b,
                                            float* __restrict__ dt,
                                            float* __restrict__ Bm,
                                            float* __restrict__ Cm,
                                            float* __restrict__ h0) {
    __shared__ unsigned int smem[3072];      // 12 KB: gemm staging / mv reduce
    const int b = blockIdx.x;
    const int t = threadIdx.x;

    if (b < 256) {
        // ---- dt GEMM tile: BM=64 x BN=128 x BK=32, bf16 MFMA ----
        unsigned int* As = smem;             // 64*16
        unsigned int* Bs = smem + 1024;      // 128*16
        const int bm = b & 31;
        const int bn = b >> 5;
        const int lane = t & 63;
        const int wn   = t >> 6;
        const int lrow = lane & 15, lq = lane >> 4;

        const int arow = t >> 2, aq = t & 3;
        const int brow = t >> 1, bhalf = t & 1;

        const float* uptr = u + (bm * 64 + arow) * 1024 + aq * 8;
        const float* wptr = dt_w + (bn * 128 + brow) * 1024 + bhalf * 16;

        f32x4 acc[4][2];
#pragma unroll
        for (int mi = 0; mi < 4; ++mi)
#pragma unroll
            for (int ni = 0; ni < 2; ++ni) acc[mi][ni] = (f32x4){0.f, 0.f, 0.f, 0.f};

        for (int k0 = 0; k0 < 1024; k0 += 32) {
            __syncthreads();
            {
                const float4* p = (const float4*)(uptr + k0);
                float4 a0 = p[0], a1 = p[1];
                uint4 ca = make_uint4(pack2(a0.x, a0.y), pack2(a0.z, a0.w),
                                      pack2(a1.x, a1.y), pack2(a1.z, a1.w));
                const int akb = aq ^ ((arow >> 1) & 3);
                *(uint4*)&As[arow * 16 + akb * 4] = ca;

                const float4* q = (const float4*)(wptr + k0);
                float4 b0 = q[0], b1 = q[1], b2 = q[2], b3 = q[3];
                uint4 d0 = make_uint4(pack2(b0.x, b0.y), pack2(b0.z, b0.w),
                                      pack2(b1.x, b1.y), pack2(b1.z, b1.w));
                uint4 d1 = make_uint4(pack2(b2.x, b2.y), pack2(b2.z, b2.w),
                                      pack2(b3.x, b3.y), pack2(b3.z, b3.w));
                const int bswz = (brow >> 1) & 3;
                const int kb0 = (bhalf * 2) ^ bswz, kb1 = (bhalf * 2 + 1) ^ bswz;
                *(uint4*)&Bs[brow * 16 + kb0 * 4] = d0;
                *(uint4*)&Bs[brow * 16 + kb1 * 4] = d1;
            }
            __syncthreads();
            short8v af[4], bf[2];
#pragma unroll
            for (int mi = 0; mi < 4; ++mi) {
                const int ar = mi * 16 + lrow;
                const int kb = lq ^ ((ar >> 1) & 3);
                af[mi] = *(const short8v*)&As[ar * 16 + kb * 4];
            }
#pragma unroll
            for (int ni = 0; ni < 2; ++ni) {
                const int br = wn * 32 + ni * 16 + lrow;
                const int kb = lq ^ ((br >> 1) & 3);
                bf[ni] = *(const short8v*)&Bs[br * 16 + kb * 4];
            }
#pragma unroll
            for (int mi = 0; mi < 4; ++mi)
#pragma unroll
                for (int ni = 0; ni < 2; ++ni)
                    acc[mi][ni] = __builtin_amdgcn_mfma_f32_16x16x32_bf16(af[mi], bf[ni], acc[mi][ni], 0, 0, 0);
        }

#pragma unroll
        for (int mi = 0; mi < 4; ++mi)
#pragma unroll
            for (int ni = 0; ni < 2; ++ni) {
                const int cg = bn * 128 + wn * 32 + ni * 16 + lrow;
                const float bv = dt_b[cg];
#pragma unroll
                for (int j = 0; j < 4; ++j) {
                    const int rg = bm * 64 + mi * 16 + lq * 4 + j;
                    dt[rg * 1024 + cg] = softplusf(acc[mi][ni][j] + bv);
                }
            }
    } else if (b < 512) {
        // ---- B/C GEMV: 8 rows/block, 2 rows/wave ----
        const int s2 = b - 256;
        const int wv = t >> 6, lane = t & 63;
#pragma unroll
        for (int rep = 0; rep < 2; ++rep) {
            const int l = s2 * 8 + wv * 2 + rep;
            const float4* u4 = (const float4*)(u + l * 1024);
            float4 ur[4];
#pragma unroll
            for (int i = 0; i < 4; ++i) ur[i] = u4[i * 64 + lane];
#pragma unroll 4
            for (int c = 0; c < 32; ++c) {
                const float4* wr = (const float4*)((c < 16) ? (B_w + c * 1024)
                                                            : (C_w + (c - 16) * 1024));
                float sv = 0.f;
#pragma unroll
                for (int i = 0; i < 4; ++i) sv += dot4(ur[i], wr[i * 64 + lane]);
#pragma unroll
                for (int off = 32; off > 0; off >>= 1) sv += __shfl_down(sv, off);
                if (lane == 0) {
                    if (c < 16) Bm[l * 16 + c] = sv + B_b[c];
                    else        Cm[l * 16 + (c - 16)] = sv + C_b[c - 16];
                }
            }
        }
    } else {
        mv_slab(b - 512, t, u, init_w, init_b, h0, (float*)smem);
    }
}

// ============ D2: p1 (blocks 0..511) + mv slabs [MV_SPLIT, 8192) =============
__global__ __launch_bounds__(256) void k_d2(const float* __restrict__ dt,
                                            const float* __restrict__ Bm,
                                            const float* __restrict__ u,
                                            const float* __restrict__ A_log,
                                            const float* __restrict__ init_w,
                                            const float* __restrict__ init_b,
                                            float* __restrict__ ap,
                                            float* __restrict__ hl,
                                            float* __restrict__ h0) {
    __shared__ float red[8];
    const int b = blockIdx.x;
    const int t = threadIdx.x;

    if (b >= 512) {
        mv_slab(MV_SPLIT + (b - 512), t, u, init_w, init_b, h0, red);
        return;
    }

    const int c    = b >> 3;
    const int dblk = b & 7;
    const int dd   = t >> 1;
    const int nh   = t & 1;
    const int d    = dblk * 128 + dd;
    float An[8];
#pragma unroll
    for (int n = 0; n < 8; ++n) An[n] = -__expf(A_log[nh * 8 + n]);
    float h[8], p[8];
#pragma unroll
    for (int n = 0; n < 8; ++n) { h[n] = 0.f; p[n] = 1.f; }

    const int l0 = c * T_CHUNK;
    for (int i = 0; i < T_CHUNK; ++i) {
        const int l = l0 + i;
        const float dtld = dt[l * D_DIM + d];
        const float uld  = u[l * D_DIM + d];
        const float4 b0 = *(const float4*)&Bm[l * 16 + nh * 8];
        const float4 b1 = *(const float4*)&Bm[l * 16 + nh * 8 + 4];
        auto body = [&](int n, float bn) {
            const float x = dtld * An[n];
            const float e = __expf(x);
            const float coef = (e - 1.f) * __builtin_amdgcn_rcpf(x + EPS_DISC);
            const float bu = coef * bn * uld;
            p[n] *= e;
            h[n] = fmaf(e, h[n], bu);
        };
        body(0, b0.x); body(1, b0.y); body(2, b0.z); body(3, b0.w);
        body(4, b1.x); body(5, b1.y); body(6, b1.z); body(7, b1.w);
    }
    const int base = c * (D_DIM * N_DIM) + d * 16 + nh * 8;
    *(float4*)&ap[base + 0] = make_float4(p[0], p[1], p[2], p[3]);
    *(float4*)&ap[base + 4] = make_float4(p[4], p[5], p[6], p[7]);
    *(float4*)&hl[base + 0] = make_float4(h[0], h[1], h[2], h[3]);
    *(float4*)&hl[base + 4] = make_float4(h[4], h[5], h[6], h[7]);
}

// ============ D3: chunk-level scan (64 steps) ================================
__global__ __launch_bounds__(64) void k_p2(const float* __restrict__ h0,
                                           float* __restrict__ ap,
                                           const float* __restrict__ hl) {
    const int ch = blockIdx.x * 64 + threadIdx.x;
    float h = h0[ch];
#pragma unroll 8
    for (int c = 0; c < NCHUNK; ++c) {
        const int idx = c * (D_DIM * N_DIM) + ch;
        const float a = ap[idx];
        const float b = hl[idx];
        ap[idx] = h;
        h = fmaf(a, h, b);
    }
}

// ============ D4: recompute with carry-in, fused epilogue ====================
__global__ __launch_bounds__(256) void k_p3(const float* __restrict__ dt,
                                            const float* __restrict__ Bm,
                                            const float* __restrict__ Cm,
                                            const float* __restrict__ u,
                                            const float* __restrict__ A_log,
                                            const float* __restrict__ hstart,
                                            const float* __restrict__ D_w,
                                            const float* __restrict__ scale,
                                            float* __restrict__ out) {
    const int t    = threadIdx.x;
    const int c    = blockIdx.x >> 3;
    const int dblk = blockIdx.x & 7;
    const int dd   = t >> 1;
    const int nh   = t & 1;
    const int d    = dblk * 128 + dd;
    float An[8];
#pragma unroll
    for (int n = 0; n < 8; ++n) An[n] = -__expf(A_log[nh * 8 + n]);
    float h[8];
    const int base = c * (D_DIM * N_DIM) + d * 16 + nh * 8;
    {
        float4 h0v = *(const float4*)&hstart[base + 0];
        float4 h1v = *(const float4*)&hstart[base + 4];
        h[0] = h0v.x; h[1] = h0v.y; h[2] = h0v.z; h[3] = h0v.w;
        h[4] = h1v.x; h[5] = h1v.y; h[6] = h1v.z; h[7] = h1v.w;
    }
    const float scl = fmaxf(scale[0], 0.5f);
    const float dw = D_w[d];
    const int l0 = c * T_CHUNK;
    for (int i = 0; i < T_CHUNK; ++i) {
        const int l = l0 + i;
        const float dtld = dt[l * D_DIM + d];
        const float uld  = u[l * D_DIM + d];
        const float4 b0 = *(const float4*)&Bm[l * 16 + nh * 8];
        const float4 b1 = *(const float4*)&Bm[l * 16 + nh * 8 + 4];
        const float4 c0 = *(const float4*)&Cm[l * 16 + nh * 8];
        const float4 c1 = *(const float4*)&Cm[l * 16 + nh * 8 + 4];
        float y = 0.f;
        auto body = [&](int n, float bn, float cn) {
            const float x = dtld * An[n];
            const float e = __expf(x);
            const float coef = (e - 1.f) * __builtin_amdgcn_rcpf(x + EPS_DISC);
            const float bu = coef * bn * uld;
            h[n] = fmaf(e, h[n], bu);
            y = fmaf(cn, h[n], y);
        };
        body(0, b0.x, c0.x); body(1, b0.y, c0.y); body(2, b0.z, c0.z); body(3, b0.w, c0.w);
        body(4, b1.x, c1.x); body(5, b1.y, c1.y); body(6, b1.z, c1.z); body(7, b1.w, c1.w);
        y += __shfl_xor(y, 1);
        if (nh == 0) {
            const float yv = fmaf(dw, uld, y);
            out[l * D_DIM + d] = softplusf(yv) * scl;
        }
    }
}

extern "C" void kernel_launch(void* const* d_in, const int* in_sizes, int n_in,
                              void* d_out, int out_size, void* d_ws, size_t ws_size,
                              hipStream_t stream) {
    const float* u      = (const float*)d_in[0];
    const float* A_log  = (const float*)d_in[1];
    const float* dt_w   = (const float*)d_in[2];
    const float* dt_b   = (const float*)d_in[3];
    const float* B_w    = (const float*)d_in[4];
    const float* B_b    = (const float*)d_in[5];
    const float* C_w    = (const float*)d_in[6];
    const float* C_b    = (const float*)d_in[7];
    const float* D_w    = (const float*)d_in[8];
    const float* scale  = (const float*)d_in[9];
    const float* init_w = (const float*)d_in[10];
    const float* init_b = (const float*)d_in[11];
    float* out = (float*)d_out;

    float* ws = (float*)d_ws;
    float* dt = ws;                        // 2048*1024 = 2097152
    float* Bm = dt + 2097152;              // 32768
    float* Cm = Bm + 32768;                // 32768
    float* h0 = Cm + 32768;                // 16384
    float* ap = h0 + 16384;                // 64*16384 = 1048576
    float* hl = ap + 1048576;              // 1048576

    hipLaunchKernelGGL(k_d1, dim3(512 + MV_SPLIT), dim3(256), 0, stream,
                       u, dt_w, dt_b, B_w, B_b, C_w, C_b, init_w, init_b,
                       dt, Bm, Cm, h0);
    hipLaunchKernelGGL(k_d2, dim3(512 + (8192 - MV_SPLIT)), dim3(256), 0, stream,
                       dt, Bm, u, A_log, init_w, init_b, ap, hl, h0);
    hipLaunchKernelGGL(k_p2, dim3(256), dim3(64), 0, stream, h0, ap, hl);
    hipLaunchKernelGGL(k_p3, dim3(512), dim3(256), 0, stream, dt, Bm, Cm, u, A_log, ap, D_w, scale, out);
}